// Round 1
// baseline (2233.160 us; speedup 1.0000x reference)
//
#include <hip/hip_runtime.h>
#include <hip/hip_bf16.h>
#include <cstdint>

// HeteroGAT on MI355X.
// Strategy: dst-CSR built once per call (histogram + block scan + fill),
// then per (layer, type): feat GEMM kernel (W column in VGPRs, lane=channel)
// and edge kernel (one wave per dst, online softmax in registers, no atomics).

#define NNODES 100000
#define NGRAPH 1024
#define NTYPES 4
#define NEDGES 800000
#define NEG_SLOPE 0.2f

// ---------------- CSR build ----------------
__global__ void count_kernel(const int* __restrict__ dst, int* __restrict__ cnt) {
    int i = blockIdx.x * 256 + threadIdx.x;
    if (i < NTYPES * NEDGES) {
        int t = i / NEDGES;
        atomicAdd(&cnt[t * NNODES + dst[i]], 1);
    }
}

// exclusive scan over T*N values, 1024 per block (256 thr x 4 items)
__global__ void scan1_kernel(const int* __restrict__ cnt, int* __restrict__ offs,
                             int* __restrict__ bsum) {
    __shared__ int sh[256];
    const int M = NTYPES * NNODES;
    int base = blockIdx.x * 1024 + threadIdx.x * 4;
    int v[4]; int tot = 0;
#pragma unroll
    for (int j = 0; j < 4; j++) {
        int idx = base + j;
        v[j] = (idx < M) ? cnt[idx] : 0;
        tot += v[j];
    }
    sh[threadIdx.x] = tot;
    __syncthreads();
    for (int off = 1; off < 256; off <<= 1) {
        int add = (threadIdx.x >= off) ? sh[threadIdx.x - off] : 0;
        __syncthreads();
        sh[threadIdx.x] += add;
        __syncthreads();
    }
    int excl = sh[threadIdx.x] - tot;
#pragma unroll
    for (int j = 0; j < 4; j++) {
        int idx = base + j;
        if (idx < M) offs[idx] = excl;
        excl += v[j];
    }
    if (threadIdx.x == 255) bsum[blockIdx.x] = sh[255];
}

__global__ void scan2_kernel(int* __restrict__ bsum, int nb) {
    __shared__ int sh[512];
    int v = (threadIdx.x < nb) ? bsum[threadIdx.x] : 0;
    sh[threadIdx.x] = v;
    __syncthreads();
    for (int off = 1; off < 512; off <<= 1) {
        int add = (threadIdx.x >= off) ? sh[threadIdx.x - off] : 0;
        __syncthreads();
        sh[threadIdx.x] += add;
        __syncthreads();
    }
    if (threadIdx.x < nb) bsum[threadIdx.x] = sh[threadIdx.x] - v;  // exclusive
}

__global__ void scan3_kernel(int* __restrict__ offs, const int* __restrict__ bsum) {
    const int M = NTYPES * NNODES;
    int i = blockIdx.x * 256 + threadIdx.x;
    if (i < M) offs[i] += bsum[i >> 10];
    if (i == 0) offs[M] = NTYPES * NEDGES;  // sentinel
}

__global__ void fill_kernel(const int* __restrict__ dst, const int* __restrict__ src,
                            const int* __restrict__ offs, int* __restrict__ fillpos,
                            int* __restrict__ csr) {
    int i = blockIdx.x * 256 + threadIdx.x;
    if (i < NTYPES * NEDGES) {
        int t = i / NEDGES;
        int idx = t * NNODES + dst[i];
        int pos = atomicAdd(&fillpos[idx], 1);
        csr[offs[idx] + pos] = src[i];
    }
}

// ---------------- embedding gather (layer-0 input) ----------------
__global__ void gather_kernel(const int* __restrict__ ids, const float* __restrict__ table,
                              float* __restrict__ h0) {
    int i = blockIdx.x * 256 + threadIdx.x;
    if (i < NNODES * 32) {
        int n = i >> 5, k = i & 31;
        h0[i] = table[ids[n] * 32 + k];
    }
}

// ---------------- feat = h @ W_t, plus el/er attention dots ----------------
// One wave per node (lane = output channel); W column cached in VGPRs.
template <int K>
__global__ __launch_bounds__(256) void feat_kernel(
    const float* __restrict__ h, const float* __restrict__ W,
    const float* __restrict__ al, const float* __restrict__ ar,
    float* __restrict__ feat, float* __restrict__ el, float* __restrict__ er) {
    int lane = threadIdx.x & 63;
    int wid = blockIdx.x * (blockDim.x >> 6) + (threadIdx.x >> 6);
    int nw = gridDim.x * (blockDim.x >> 6);
    float Wc[K];
#pragma unroll
    for (int k = 0; k < K; k++) Wc[k] = W[k * 64 + lane];
    float alr = al[lane];  // al[t][h][d] flat == al[t*64 + lane]
    float arr = ar[lane];
    for (int n = wid; n < NNODES; n += nw) {
        const float* hp = h + n * K;
        float acc = 0.f;
#pragma unroll
        for (int k4 = 0; k4 < K; k4 += 4) {
            float4 hv = *reinterpret_cast<const float4*>(hp + k4);  // broadcast load
            acc = fmaf(hv.x, Wc[k4 + 0], acc);
            acc = fmaf(hv.y, Wc[k4 + 1], acc);
            acc = fmaf(hv.z, Wc[k4 + 2], acc);
            acc = fmaf(hv.w, Wc[k4 + 3], acc);
        }
        feat[n * 64 + lane] = acc;
        float p = acc * alr, q = acc * arr;
#pragma unroll
        for (int s = 1; s < 16; s <<= 1) {
            p += __shfl_xor(p, s, 64);
            q += __shfl_xor(q, s, 64);
        }
        if ((lane & 15) == 0) {
            el[n * 4 + (lane >> 4)] = p;
            er[n * 4 + (lane >> 4)] = q;
        }
    }
}

// ---------------- edge pass: one wave per dst, online softmax ----------------
template <bool FIRST, bool RELU>
__global__ __launch_bounds__(256) void edge_kernel(
    const int* __restrict__ csr, const int* __restrict__ offs,  // offs already + t*N
    const float* __restrict__ el, const float* __restrict__ er,
    const float* __restrict__ feat, const float* __restrict__ b,
    float* __restrict__ hnext) {
    int lane = threadIdx.x & 63;
    int d = blockIdx.x * (blockDim.x >> 6) + (threadIdx.x >> 6);
    if (d >= NNODES) return;
    int h4 = lane >> 4;
    int o0 = offs[d], o1 = offs[d + 1];
    float erv = er[d * 4 + h4];
    float m = -INFINITY, z = 0.f, acc = 0.f;
    for (int i = o0; i < o1; i++) {
        int s = csr[i];                      // wave-uniform broadcast load
        float e = el[s * 4 + h4] + erv;
        e = e > 0.f ? e : NEG_SLOPE * e;     // leaky relu
        float f = feat[s * 64 + lane];       // coalesced 256B gather
        float mn = fmaxf(m, e);
        float corr = __expf(m - mn);         // first iter: exp(-inf)=0, 0*0=0 ok
        float p = __expf(e - mn);
        z = z * corr + p;
        acc = acc * corr + p * f;
        m = mn;
    }
    float val = (o1 > o0) ? acc / z : 0.f;
    val += b[lane];
    float out = FIRST ? val : hnext[d * 64 + lane] + val;
    if (RELU) out = fmaxf(out, 0.f);
    hnext[d * 64 + lane] = out;
}

// ---------------- readout: segment_sum over sorted graph_ids ----------------
__global__ void embed_kernel(const int* __restrict__ gid, const float* __restrict__ h,
                             float* __restrict__ out) {
    int bg = blockIdx.x;
    int lane = threadIdx.x;
    int lo = 0, hi = NNODES;
    while (lo < hi) { int mid = (lo + hi) >> 1; if (gid[mid] < bg) lo = mid + 1; else hi = mid; }
    int start = lo;
    hi = NNODES;
    while (lo < hi) { int mid = (lo + hi) >> 1; if (gid[mid] < bg + 1) lo = mid + 1; else hi = mid; }
    int end = lo;
    float s = 0.f;
    for (int n = start; n < end; n++) s += h[n * 64 + lane];
    out[bg * 64 + lane] = s;
}

__global__ void score_kernel(const float* __restrict__ ow1, const float* __restrict__ ob1,
                             const float* __restrict__ ow2, const float* __restrict__ ob2,
                             const float* __restrict__ embed, float* __restrict__ score) {
    __shared__ float wc[64];
    __shared__ float cst;
    int tid = threadIdx.x;
    if (tid < 64) {
        float s = 0.f;
        for (int j = 0; j < 32; j++) s += ow1[tid * 32 + j] * ow2[j];
        wc[tid] = s;
    }
    if (tid == 64) {
        float s = 0.f;
        for (int j = 0; j < 32; j++) s += ob1[j] * ow2[j];
        cst = s + ob2[0];
    }
    __syncthreads();
    int bg = blockIdx.x * blockDim.x + tid;
    if (bg < NGRAPH) {
        float s = cst;
        for (int c = 0; c < 64; c++) s = fmaf(embed[bg * 64 + c], wc[c], s);
        score[bg] = s;
    }
}

extern "C" void kernel_launch(void* const* d_in, const int* in_sizes, int n_in,
                              void* d_out, int out_size, void* d_ws, size_t ws_size,
                              hipStream_t stream) {
    const int* node_ids  = (const int*)d_in[0];
    const int* graph_ids = (const int*)d_in[1];
    const int* src       = (const int*)d_in[2];
    const int* dst       = (const int*)d_in[3];
    const float* table   = (const float*)d_in[4];
    const float* Wm[3]  = {(const float*)d_in[5],  (const float*)d_in[9],  (const float*)d_in[13]};
    const float* alm[3] = {(const float*)d_in[6],  (const float*)d_in[10], (const float*)d_in[14]};
    const float* arm[3] = {(const float*)d_in[7],  (const float*)d_in[11], (const float*)d_in[15]};
    const float* bm[3]  = {(const float*)d_in[8],  (const float*)d_in[12], (const float*)d_in[16]};
    const float* ow1 = (const float*)d_in[17];
    const float* ob1 = (const float*)d_in[18];
    const float* ow2 = (const float*)d_in[19];
    const float* ob2 = (const float*)d_in[20];

    float* out_embed = (float*)d_out;
    float* out_score = out_embed + NGRAPH * 64;

    // ---- workspace layout (elements; all offsets 16B aligned) ----
    char* w = (char*)d_ws;
    int* cnt = (int*)w;       w += 4ull * NTYPES * NNODES;        // 400000
    int* offs = (int*)w;      w += 4ull * (NTYPES * NNODES + 64); // 400064
    int* fillpos = (int*)w;   w += 4ull * NTYPES * NNODES;        // 400000
    int* bsum = (int*)w;      w += 4ull * 512;
    int* csr = (int*)w;       w += 4ull * NTYPES * NEDGES;        // 3.2M
    float* hA = (float*)w;    w += 4ull * NNODES * 64;
    float* hB = (float*)w;    w += 4ull * NNODES * 64;
    float* feat = (float*)w;  w += 4ull * NNODES * 64;
    float* elb = (float*)w;   w += 4ull * NNODES * 4;
    float* erb = (float*)w;   w += 4ull * NNODES * 4;

    const int M = NTYPES * NNODES;
    const int TE = NTYPES * NEDGES;
    const int NB = (M + 1023) / 1024;  // 391 (<=512 for scan2)

    // ---- CSR build (amortized over 3 layers) ----
    hipMemsetAsync(cnt, 0, sizeof(int) * M, stream);
    hipMemsetAsync(fillpos, 0, sizeof(int) * M, stream);
    count_kernel<<<(TE + 255) / 256, 256, 0, stream>>>(dst, cnt);
    scan1_kernel<<<NB, 256, 0, stream>>>(cnt, offs, bsum);
    scan2_kernel<<<1, 512, 0, stream>>>(bsum, NB);
    scan3_kernel<<<(M + 255) / 256, 256, 0, stream>>>(offs, bsum);
    fill_kernel<<<(TE + 255) / 256, 256, 0, stream>>>(dst, src, offs, fillpos, csr);

    // ---- layer-0 input ----
    gather_kernel<<<(NNODES * 32 + 255) / 256, 256, 0, stream>>>(node_ids, table, hA);

    float* hin = hA;
    float* hout = hB;
    const int EDGE_GRID = (NNODES + 3) / 4;  // 4 waves / 256-thread block

    for (int L = 0; L < 3; L++) {
        const int K = (L == 0) ? 32 : 64;
        for (int t = 0; t < NTYPES; t++) {
            const float* Wt = Wm[L] + (size_t)t * K * 64;
            const float* alt = alm[L] + t * 64;
            const float* art = arm[L] + t * 64;
            const float* bt = bm[L] + t * 64;
            if (L == 0)
                feat_kernel<32><<<2048, 256, 0, stream>>>(hin, Wt, alt, art, feat, elb, erb);
            else
                feat_kernel<64><<<2048, 256, 0, stream>>>(hin, Wt, alt, art, feat, elb, erb);

            const int* offs_t = offs + t * NNODES;
            bool relu = (L < 2) && (t == NTYPES - 1);
            if (t == 0)
                edge_kernel<true, false><<<EDGE_GRID, 256, 0, stream>>>(csr, offs_t, elb, erb, feat, bt, hout);
            else if (relu)
                edge_kernel<false, true><<<EDGE_GRID, 256, 0, stream>>>(csr, offs_t, elb, erb, feat, bt, hout);
            else
                edge_kernel<false, false><<<EDGE_GRID, 256, 0, stream>>>(csr, offs_t, elb, erb, feat, bt, hout);
        }
        float* tmp = hin; hin = hout; hout = tmp;
    }

    embed_kernel<<<NGRAPH, 64, 0, stream>>>(graph_ids, hin, out_embed);
    score_kernel<<<(NGRAPH + 255) / 256, 256, 0, stream>>>(ow1, ob1, ow2, ob2, out_embed, out_score);
}

// Round 4
// 1584.418 us; speedup vs baseline: 1.4095x; 1.4095x over previous
//
#include <hip/hip_runtime.h>
#include <hip/hip_bf16.h>
#include <cstdint>

// HeteroGAT on MI355X.
// CSR build: coarse 256-node buckets -> frontier-local pair scatter -> per-bucket
// LDS-staged fine sort (coalesced csr writes).
// Edge pass: one wave per dst, 16-edge chunks, wave-wide exp, unrolled PV gather.

#define NNODES 100000
#define NGRAPH 1024
#define NTYPES 4
#define NEDGES 800000
#define NEG_SLOPE 0.2f

#define NBPT 391                 // buckets per type (256 nodes each)
#define NBKT (NTYPES * NBPT)     // 1564 total buckets
#define TE (NTYPES * NEDGES)     // 3.2M edges
#define BCAP 4608                // LDS staging capacity per bucket (mean 2048, sigma ~45)

// ---------------- CSR pass A1: coarse bucket histogram ----------------
__global__ __launch_bounds__(256) void countb_kernel(const int* __restrict__ dst,
                                                     int* __restrict__ bcnt) {
    __shared__ int h[NBKT];
    int tid = threadIdx.x;
    for (int k = tid; k < NBKT; k += 256) h[k] = 0;
    __syncthreads();
    const int CHUNK = (TE + 511) / 512;  // 6250
    int start = blockIdx.x * CHUNK;
    int end = start + CHUNK; if (end > TE) end = TE;
    for (int i = start + tid; i < end; i += 256) {
        int t = i / NEDGES;
        int b = t * NBPT + (dst[i] >> 8);
        atomicAdd(&h[b], 1);
    }
    __syncthreads();
    for (int k = tid; k < NBKT; k += 256) {
        int v = h[k];
        if (v) atomicAdd(&bcnt[k], v);
    }
}

// ---------------- CSR pass A2: scan buckets, init cursors ----------------
__global__ __launch_bounds__(256) void scanb_kernel(const int* __restrict__ bcnt,
                                                    int* __restrict__ boffs,
                                                    int* __restrict__ cursor,
                                                    int* __restrict__ offs) {
    __shared__ int sh[256];
    int tid = threadIdx.x;
    const int PER = 7;  // 256*7 = 1792 >= 1564
    int v[PER]; int tot = 0;
#pragma unroll
    for (int j = 0; j < PER; j++) {
        int idx = tid * PER + j;
        v[j] = (idx < NBKT) ? bcnt[idx] : 0;
        tot += v[j];
    }
    sh[tid] = tot;
    __syncthreads();
    for (int off = 1; off < 256; off <<= 1) {
        int a = (tid >= off) ? sh[tid - off] : 0;
        __syncthreads();
        sh[tid] += a;
        __syncthreads();
    }
    int excl = sh[tid] - tot;
#pragma unroll
    for (int j = 0; j < PER; j++) {
        int idx = tid * PER + j;
        if (idx < NBKT) { boffs[idx] = excl; cursor[idx * 16] = excl; }
        excl += v[j];
    }
    if (tid == 0) { boffs[NBKT] = TE; offs[NTYPES * NNODES] = TE; }
}

// ---------------- CSR pass A3: scatter packed pairs at bucket cursors ----------------
__global__ __launch_bounds__(256) void scatb_kernel(const int* __restrict__ src,
                                                    const int* __restrict__ dst,
                                                    int* __restrict__ cursor,
                                                    int* __restrict__ pairbuf) {
    int i = blockIdx.x * 256 + threadIdx.x;
    if (i >= TE) return;
    int t = i / NEDGES;
    int d = dst[i];
    int b = t * NBPT + (d >> 8);
    int pos = atomicAdd(&cursor[b * 16], 1);
    pairbuf[pos] = src[i] | ((d & 255) << 17);  // src < 2^17, local node in bits 17..24
}

// ---------------- CSR pass B: per-bucket fine sort, coalesced csr write ----------------
__global__ __launch_bounds__(256) void fillb_kernel(const int* __restrict__ boffs,
                                                    const int* __restrict__ pairbuf,
                                                    int* __restrict__ offs,
                                                    int* __restrict__ csr) {
    __shared__ int hist[256];
    __shared__ int sh[256];
    __shared__ int cur[256];
    __shared__ int stage[BCAP];
    int tid = threadIdx.x;
    int b = blockIdx.x;
    int t = b / NBPT, bi = b % NBPT;
    int nbase = bi << 8;
    int e0 = boffs[b], e1 = boffs[b + 1];
    int cntE = e1 - e0;
    hist[tid] = 0;
    __syncthreads();
    for (int i = e0 + tid; i < e1; i += 256) atomicAdd(&hist[pairbuf[i] >> 17], 1);
    __syncthreads();
    int hv = hist[tid];
    sh[tid] = hv;
    __syncthreads();
    for (int off = 1; off < 256; off <<= 1) {
        int a = (tid >= off) ? sh[tid - off] : 0;
        __syncthreads();
        sh[tid] += a;
        __syncthreads();
    }
    int excl = sh[tid] - hv;
    int n = nbase + tid;
    if (n < NNODES) offs[t * NNODES + n] = e0 + excl;
    cur[tid] = excl;
    __syncthreads();
    if (cntE <= BCAP) {
        for (int i = e0 + tid; i < e1; i += 256) {
            int v = pairbuf[i];
            int p = atomicAdd(&cur[v >> 17], 1);
            stage[p] = v & 0x1FFFF;
        }
        __syncthreads();
        for (int i = tid; i < cntE; i += 256) csr[e0 + i] = stage[i];
    } else {  // overflow fallback (statistically never: mean 2048, cap 4608)
        for (int i = e0 + tid; i < e1; i += 256) {
            int v = pairbuf[i];
            int p = atomicAdd(&cur[v >> 17], 1);
            csr[e0 + p] = v & 0x1FFFF;
        }
    }
}

// ---------------- embedding gather (layer-0 input) ----------------
__global__ void gather_kernel(const int* __restrict__ ids, const float* __restrict__ table,
                              float* __restrict__ h0) {
    int i = blockIdx.x * 256 + threadIdx.x;
    if (i < NNODES * 32) {
        int n = i >> 5, k = i & 31;
        h0[i] = table[ids[n] * 32 + k];
    }
}

// ---------------- feat = h @ W_t, plus el/er attention dots ----------------
template <int K>
__global__ __launch_bounds__(256) void feat_kernel(
    const float* __restrict__ h, const float* __restrict__ W,
    const float* __restrict__ al, const float* __restrict__ ar,
    float* __restrict__ feat, float* __restrict__ el, float* __restrict__ er) {
    int lane = threadIdx.x & 63;
    int wid = blockIdx.x * (blockDim.x >> 6) + (threadIdx.x >> 6);
    int nw = gridDim.x * (blockDim.x >> 6);
    float Wc[K];
#pragma unroll
    for (int k = 0; k < K; k++) Wc[k] = W[k * 64 + lane];
    float alr = al[lane];
    float arr = ar[lane];
    for (int n = wid; n < NNODES; n += nw) {
        const float* hp = h + n * K;
        float acc = 0.f;
#pragma unroll
        for (int k4 = 0; k4 < K; k4 += 4) {
            float4 hv = *reinterpret_cast<const float4*>(hp + k4);
            acc = fmaf(hv.x, Wc[k4 + 0], acc);
            acc = fmaf(hv.y, Wc[k4 + 1], acc);
            acc = fmaf(hv.z, Wc[k4 + 2], acc);
            acc = fmaf(hv.w, Wc[k4 + 3], acc);
        }
        feat[n * 64 + lane] = acc;
        float p = acc * alr, q = acc * arr;
#pragma unroll
        for (int s = 1; s < 16; s <<= 1) {
            p += __shfl_xor(p, s, 64);
            q += __shfl_xor(q, s, 64);
        }
        if ((lane & 15) == 0) {
            el[n * 4 + (lane >> 4)] = p;
            er[n * 4 + (lane >> 4)] = q;
        }
    }
}

// ---------------- edge pass: one wave per dst, 16-edge chunks ----------------
// Phase 1 layout: lane = 4*edge_slot + head  (16 edges x 4 heads)
// Phase 2 layout: lane = channel c, head = c>>4
template <bool FIRST, bool RELU>
__global__ __launch_bounds__(256) void edge_kernel(
    const int* __restrict__ csr, const int* __restrict__ offs,  // offs already + t*N
    const float* __restrict__ el, const float* __restrict__ er,
    const float* __restrict__ feat, const float* __restrict__ b,
    float* __restrict__ hnext) {
    int lane = threadIdx.x & 63;
    int d = blockIdx.x * 4 + (threadIdx.x >> 6);
    if (d >= NNODES) return;
    int hp = lane & 3;   // phase-1 head
    int h2 = lane >> 4;  // phase-2 head
    int j = lane >> 2;   // phase-1 edge slot
    int o0 = offs[d], o1 = offs[d + 1];
    float erv = er[d * 4 + hp];
    float m = -INFINITY, z = 0.f, acc = 0.f;
    for (int base = o0; base < o1; base += 16) {
        int cnt = o1 - base; if (cnt > 16) cnt = 16;
        int idx = base + j; if (idx > o1 - 1) idx = o1 - 1;  // clamp in-bounds
        int s = csr[idx];                    // coalesced 64B read
        bool valid = j < cnt;
        float e = el[s * 4 + hp] + erv;      // 16-line gather
        e = e > 0.f ? e : NEG_SLOPE * e;
        if (!valid) e = -INFINITY;
        float cm = e;                        // per-head chunk max (reduce over edge slots)
        cm = fmaxf(cm, __shfl_xor(cm, 4));
        cm = fmaxf(cm, __shfl_xor(cm, 8));
        cm = fmaxf(cm, __shfl_xor(cm, 16));
        cm = fmaxf(cm, __shfl_xor(cm, 32));
        float mn = fmaxf(m, cm);
        float corr = __expf(m - mn);         // first chunk: exp(-inf)=0
        float p = valid ? __expf(e - mn) : 0.f;  // one wave-wide exp for 64 (edge,head)
        float zc = p;
        zc += __shfl_xor(zc, 4);
        zc += __shfl_xor(zc, 8);
        zc += __shfl_xor(zc, 16);
        zc += __shfl_xor(zc, 32);
        z = z * corr + zc;
        float corr2 = __shfl(corr, h2);      // corr for this channel's head
        acc *= corr2;
#pragma unroll
        for (int k = 0; k < 16; k++) {       // PV: 16 independent feat gathers
            int kk = (k < cnt) ? k : 0;      // clamped slots hit slot-0's lines (L1)
            int sk = __shfl(s, kk << 2);
            float pk = __shfl(p, (kk << 2) | h2);
            if (k >= cnt) pk = 0.f;
            acc = fmaf(pk, feat[sk * 64 + lane], acc);
        }
        m = mn;
    }
    float z2 = __shfl(z, h2);
    float val = (o1 > o0) ? acc / z2 : 0.f;
    val += b[lane];
    float out = FIRST ? val : hnext[d * 64 + lane] + val;
    if (RELU) out = fmaxf(out, 0.f);
    hnext[d * 64 + lane] = out;
}

// ---------------- readout ----------------
__global__ void embed_kernel(const int* __restrict__ gid, const float* __restrict__ h,
                             float* __restrict__ out) {
    int bg = blockIdx.x;
    int lane = threadIdx.x;
    int lo = 0, hi = NNODES;
    while (lo < hi) { int mid = (lo + hi) >> 1; if (gid[mid] < bg) lo = mid + 1; else hi = mid; }
    int start = lo;
    hi = NNODES;
    while (lo < hi) { int mid = (lo + hi) >> 1; if (gid[mid] < bg + 1) lo = mid + 1; else hi = mid; }
    int end = lo;
    float s = 0.f;
    for (int n = start; n < end; n++) s += h[n * 64 + lane];
    out[bg * 64 + lane] = s;
}

__global__ void score_kernel(const float* __restrict__ ow1, const float* __restrict__ ob1,
                             const float* __restrict__ ow2, const float* __restrict__ ob2,
                             const float* __restrict__ embed, float* __restrict__ score) {
    __shared__ float wc[64];
    __shared__ float cst;
    int tid = threadIdx.x;
    if (tid < 64) {
        float s = 0.f;
        for (int j = 0; j < 32; j++) s += ow1[tid * 32 + j] * ow2[j];
        wc[tid] = s;
    }
    if (tid == 64) {
        float s = 0.f;
        for (int j = 0; j < 32; j++) s += ob1[j] * ow2[j];
        cst = s + ob2[0];
    }
    __syncthreads();
    int bg = blockIdx.x * blockDim.x + tid;
    if (bg < NGRAPH) {
        float s = cst;
        for (int c = 0; c < 64; c++) s = fmaf(embed[bg * 64 + c], wc[c], s);
        score[bg] = s;
    }
}

extern "C" void kernel_launch(void* const* d_in, const int* in_sizes, int n_in,
                              void* d_out, int out_size, void* d_ws, size_t ws_size,
                              hipStream_t stream) {
    const int* node_ids  = (const int*)d_in[0];
    const int* graph_ids = (const int*)d_in[1];
    const int* src       = (const int*)d_in[2];
    const int* dst       = (const int*)d_in[3];
    const float* table   = (const float*)d_in[4];
    const float* Wm[3]  = {(const float*)d_in[5],  (const float*)d_in[9],  (const float*)d_in[13]};
    const float* alm[3] = {(const float*)d_in[6],  (const float*)d_in[10], (const float*)d_in[14]};
    const float* arm[3] = {(const float*)d_in[7],  (const float*)d_in[11], (const float*)d_in[15]};
    const float* bm[3]  = {(const float*)d_in[8],  (const float*)d_in[12], (const float*)d_in[16]};
    const float* ow1 = (const float*)d_in[17];
    const float* ob1 = (const float*)d_in[18];
    const float* ow2 = (const float*)d_in[19];
    const float* ob2 = (const float*)d_in[20];

    float* out_embed = (float*)d_out;
    float* out_score = out_embed + NGRAPH * 64;

    // ---- workspace layout ----
    char* w = (char*)d_ws;
    float* hA = (float*)w;    w += 4ull * NNODES * 64;          // 25.6MB
    float* hB = (float*)w;    w += 4ull * NNODES * 64;          // 25.6MB
    float* feat = (float*)w;  w += 4ull * NNODES * 64;          // 25.6MB
    int* csr = (int*)w;       w += 4ull * TE;                   // 12.8MB
    int* offs = (int*)w;      w += 4ull * (NTYPES * NNODES + 16);
    float* elb = (float*)w;   w += 4ull * NNODES * 4;
    float* erb = (float*)w;   w += 4ull * NNODES * 4;
    int* bcnt = (int*)w;      w += 4ull * ((NBKT + 15) & ~15);
    int* boffs = (int*)w;     w += 4ull * ((NBKT + 16) & ~15);
    int* cursor = (int*)w;    w += 4ull * NBKT * 16;            // padded: 1 cursor / 64B
    int* pairbuf = (int*)hA;  // aliases hA: dead before gather_kernel writes hA

    // ---- CSR build ----
    hipMemsetAsync(bcnt, 0, sizeof(int) * NBKT, stream);
    countb_kernel<<<512, 256, 0, stream>>>(dst, bcnt);
    scanb_kernel<<<1, 256, 0, stream>>>(bcnt, boffs, cursor, offs);
    scatb_kernel<<<(TE + 255) / 256, 256, 0, stream>>>(src, dst, cursor, pairbuf);
    fillb_kernel<<<NBKT, 256, 0, stream>>>(boffs, pairbuf, offs, csr);

    // ---- layer-0 input ----
    gather_kernel<<<(NNODES * 32 + 255) / 256, 256, 0, stream>>>(node_ids, table, hA);

    float* hin = hA;
    float* hout = hB;
    const int EDGE_GRID = (NNODES + 3) / 4;

    for (int L = 0; L < 3; L++) {
        for (int t = 0; t < NTYPES; t++) {
            const int K = (L == 0) ? 32 : 64;
            const float* Wt = Wm[L] + (size_t)t * K * 64;
            const float* alt = alm[L] + t * 64;
            const float* art = arm[L] + t * 64;
            const float* bt = bm[L] + t * 64;
            if (L == 0)
                feat_kernel<32><<<2048, 256, 0, stream>>>(hin, Wt, alt, art, feat, elb, erb);
            else
                feat_kernel<64><<<2048, 256, 0, stream>>>(hin, Wt, alt, art, feat, elb, erb);

            const int* offs_t = offs + t * NNODES;
            bool relu = (L < 2) && (t == NTYPES - 1);
            if (t == 0)
                edge_kernel<true, false><<<EDGE_GRID, 256, 0, stream>>>(csr, offs_t, elb, erb, feat, bt, hout);
            else if (relu)
                edge_kernel<false, true><<<EDGE_GRID, 256, 0, stream>>>(csr, offs_t, elb, erb, feat, bt, hout);
            else
                edge_kernel<false, false><<<EDGE_GRID, 256, 0, stream>>>(csr, offs_t, elb, erb, feat, bt, hout);
        }
        float* tmp = hin; hin = hout; hout = tmp;
    }

    embed_kernel<<<NGRAPH, 64, 0, stream>>>(graph_ids, hin, out_embed);
    score_kernel<<<(NGRAPH + 255) / 256, 256, 0, stream>>>(ow1, ob1, ow2, ob2, out_embed, out_score);
}